// Round 1
// baseline (551.436 us; speedup 1.0000x reference)
//
#include <hip/hip_runtime.h>
#include <math.h>

#define N_NODES 100000
#define NG 100
#define N_PER 1000
#define N_EDGES 3200000
#define K_TOP 800
#define F_IN 128
#define F_MID 16
#define F_OUT 256
#define CAP 96

// ---------------- zero init (ws/out are poisoned 0xAA) ----------------
__global__ void k_zero(int* __restrict__ cnt, float* __restrict__ out) {
    int i = blockIdx.x * blockDim.x + threadIdx.x;
    if (i < N_NODES) cnt[i] = 0;
    if (i < NG * F_OUT) out[i] = 0.f;
}

// ---------------- build padded CSR by dst ----------------
__global__ void k_build_csr(const int* __restrict__ ei, int* __restrict__ cnt,
                            int* __restrict__ csr) {
    int e = blockIdx.x * blockDim.x + threadIdx.x;
    if (e < N_EDGES) {
        int s = ei[e];             // src row
        int d = ei[N_EDGES + e];   // dst row
        int p = atomicAdd(&cnt[d], 1);
        if (p < CAP) csr[(size_t)d * CAP + p] = s;
    }
}

// ---------------- xw1 = x @ W1  (100000x128 @ 128x16) ----------------
__global__ void k_gemm1(const float* __restrict__ x, const float* __restrict__ W1,
                        float* __restrict__ xw1) {
    __shared__ float xs[16 * 132];   // stride 132 -> conflict-free across 4 node-groups
    __shared__ float ws[128 * 16];
    int t = threadIdx.x;
    int n0 = blockIdx.x * 16;
    const float* xp = x + (size_t)n0 * F_IN;
    for (int i = t; i < 16 * F_IN; i += 256) {
        int n = i / F_IN, k = i % F_IN;
        xs[n * 132 + k] = xp[i];
    }
    for (int i = t; i < F_IN * F_MID; i += 256) ws[i] = W1[i];
    __syncthreads();
    int node = t >> 4, j = t & 15;
    const float* xr = xs + node * 132;
    float acc = 0.f;
#pragma unroll 16
    for (int k = 0; k < F_IN; k++) acc += xr[k] * ws[k * F_MID + j];
    xw1[(size_t)(n0 + node) * F_MID + j] = acc;
}

// ---------------- dis1 = rsqrt(indeg + 1) ----------------
__global__ void k_deg1(const int* __restrict__ cnt, float* __restrict__ dis1) {
    int i = blockIdx.x * blockDim.x + threadIdx.x;
    if (i < N_NODES) dis1[i] = 1.0f / sqrtf((float)cnt[i] + 1.0f);
}

// ---------------- conv1 aggregation + bias + relu -> h ----------------
// h[i] = relu( dis1[i]*sum_e xw1[src]*dis1[src] + xw1[i]*dis1[i]^2 + b1 )
__global__ void k_agg1(const float* __restrict__ xw1, const float* __restrict__ dis1,
                       const int* __restrict__ cnt, const int* __restrict__ csr,
                       const float* __restrict__ b1, float* __restrict__ h) {
    int gid = blockIdx.x * 16 + (threadIdx.x >> 4);
    int j = threadIdx.x & 15;
    if (gid >= N_NODES) return;
    int c = cnt[gid]; if (c > CAP) c = CAP;
    const int* cp = csr + (size_t)gid * CAP;
    float sum = 0.f;
    for (int k = 0; k < c; k++) {
        int s = cp[k];
        sum += xw1[(size_t)s * F_MID + j] * dis1[s];
    }
    float di = dis1[gid];
    float v = sum * di + xw1[(size_t)gid * F_MID + j] * di * di + b1[j];
    h[(size_t)gid * F_MID + j] = fmaxf(v, 0.f);
}

// ---------------- SAGPool score ----------------
// score[i] = tanh( (sum_e h[src]) . w_rel + h[i] . w_root + b_rel )
__global__ void k_score(const float* __restrict__ h, const int* __restrict__ cnt,
                        const int* __restrict__ csr, const float* __restrict__ w_rel,
                        const float* __restrict__ w_root, const float* __restrict__ b_rel,
                        float* __restrict__ score) {
    int gid = blockIdx.x * 16 + (threadIdx.x >> 4);
    int j = threadIdx.x & 15;
    if (gid >= N_NODES) return;
    int c = cnt[gid]; if (c > CAP) c = CAP;
    const int* cp = csr + (size_t)gid * CAP;
    float aggj = 0.f;
    for (int k = 0; k < c; k++) {
        int s = cp[k];
        aggj += h[(size_t)s * F_MID + j];
    }
    float val = aggj * w_rel[j] + h[(size_t)gid * F_MID + j] * w_root[j];
    for (int o = 8; o > 0; o >>= 1) val += __shfl_xor(val, o, 16);
    if (j == 0) score[gid] = tanhf(val + b_rel[0]);
}

// ---------------- per-graph top-K=800 -> mask, gated score ----------------
__global__ void k_topk(const float* __restrict__ score, float* __restrict__ maskv,
                       float* __restrict__ sg) {
    __shared__ float s[N_PER];
    __shared__ float ss[1024];
    __shared__ int cnt_gt;
    int g = blockIdx.x, t = threadIdx.x;
    const float* sp = score + (size_t)g * N_PER;
    for (int i = t; i < N_PER; i += 256) { float v = sp[i]; s[i] = v; ss[i] = v; }
    for (int i = t; i < 1024; i += 256) if (i >= N_PER) ss[i] = -1e30f;
    if (t == 0) cnt_gt = 0;
    __syncthreads();
    // bitonic sort ascending over 1024
    for (int k2 = 2; k2 <= 1024; k2 <<= 1) {
        for (int j2 = k2 >> 1; j2 > 0; j2 >>= 1) {
            for (int i = t; i < 1024; i += 256) {
                int ixj = i ^ j2;
                if (ixj > i) {
                    float a = ss[i], b = ss[ixj];
                    bool asc = ((i & k2) == 0);
                    if ((a > b) == asc) { ss[i] = b; ss[ixj] = a; }
                }
            }
            __syncthreads();
        }
    }
    float thr = ss[1024 - K_TOP];  // K-th largest
    int loc = 0;
    for (int i = t; i < N_PER; i += 256) if (s[i] > thr) loc++;
    atomicAdd(&cnt_gt, loc);
    __syncthreads();
    int need = K_TOP - cnt_gt;  // #ties to take, lowest index first (top_k semantics)
    for (int i = t; i < N_PER; i += 256) {
        float v = s[i];
        float m;
        if (v > thr) m = 1.f;
        else if (v < thr) m = 0.f;
        else {
            int r = 0;
            for (int l = 0; l < i; l++) if (s[l] == thr) r++;
            m = (r < need) ? 1.f : 0.f;
        }
        maskv[(size_t)g * N_PER + i] = m;
        sg[(size_t)g * N_PER + i] = v * m;
    }
}

// ---------------- deg2/dis2 + per-node src weight ----------------
// deg2[i] = mask[i]*(sum_e mask[src] + 1); dis2 = deg2>0 ? rsqrt : 0; wsrc = sg*dis2
__global__ void k_deg2(const float* __restrict__ maskv, const float* __restrict__ sg,
                       const int* __restrict__ cnt, const int* __restrict__ csr,
                       float* __restrict__ dis2, float* __restrict__ wsrcv) {
    int gid = blockIdx.x * 16 + (threadIdx.x >> 4);
    int j = threadIdx.x & 15;
    if (gid >= N_NODES) return;
    int c = cnt[gid]; if (c > CAP) c = CAP;
    const int* cp = csr + (size_t)gid * CAP;
    float sum = 0.f;
    for (int k = j; k < c; k += 16) sum += maskv[cp[k]];
    for (int o = 8; o > 0; o >>= 1) sum += __shfl_xor(sum, o, 16);
    if (j == 0) {
        float mi = maskv[gid];
        float d2 = mi * (sum + 1.f);
        float di = (d2 > 0.f) ? 1.0f / sqrtf(d2) : 0.f;
        dis2[gid] = di;
        wsrcv[gid] = sg[gid] * di;
    }
}

// ---------------- conv2 pre-GEMM aggregation in F_MID dims ----------------
// pre[i] = dis2[i]*sum_e h[src]*sg[src]*dis2[src] + h[i]*sg[i]*dis2[i]^2
__global__ void k_pre(const float* __restrict__ h, const float* __restrict__ sg,
                      const float* __restrict__ dis2, const float* __restrict__ wsrcv,
                      const int* __restrict__ cnt, const int* __restrict__ csr,
                      float* __restrict__ pre) {
    int gid = blockIdx.x * 16 + (threadIdx.x >> 4);
    int j = threadIdx.x & 15;
    if (gid >= N_NODES) return;
    float di = dis2[gid];
    if (di == 0.f) {  // masked-out node: pre = 0 (uniform within 16-lane group)
        pre[(size_t)gid * F_MID + j] = 0.f;
        return;
    }
    int c = cnt[gid]; if (c > CAP) c = CAP;
    const int* cp = csr + (size_t)gid * CAP;
    float sum = 0.f;
    for (int k = 0; k < c; k++) {
        int s = cp[k];
        sum += h[(size_t)s * F_MID + j] * wsrcv[s];
    }
    float v = sum * di + h[(size_t)gid * F_MID + j] * sg[gid] * di * di;
    pre[(size_t)gid * F_MID + j] = v;
}

// ---------------- fused GEMM2 + relu + masked mean-pool ----------------
// out[g,f] = (1/800) * sum_{i in g, mask=1} relu( pre[i] . W2[:,f] + b2[f] )
#define NCHUNK 4
#define CH_NODES (N_PER / NCHUNK)  // 250
__global__ void k_final(const float* __restrict__ pre, const float* __restrict__ maskv,
                        const float* __restrict__ W2, const float* __restrict__ b2,
                        float* __restrict__ out) {
    int g = blockIdx.x / NCHUNK;
    int ch = blockIdx.x % NCHUNK;
    int f = threadIdx.x;  // 0..255
    float w2c[F_MID];
#pragma unroll
    for (int j = 0; j < F_MID; j++) w2c[j] = W2[j * F_OUT + f];
    float bf = b2[f];
    __shared__ float tile[32][F_MID];
    __shared__ float mv[32];
    float acc = 0.f;
    int nbeg = g * N_PER + ch * CH_NODES;
    for (int t0 = 0; t0 < CH_NODES; t0 += 32) {
        int nn = min(32, CH_NODES - t0);
        __syncthreads();
        for (int i = threadIdx.x; i < nn * F_MID; i += 256)
            tile[i / F_MID][i % F_MID] = pre[(size_t)(nbeg + t0) * F_MID + i];
        for (int i = threadIdx.x; i < nn; i += 256) mv[i] = maskv[nbeg + t0 + i];
        __syncthreads();
        for (int n = 0; n < nn; n++) {
            if (mv[n] != 0.f) {  // block-uniform branch
                float v = bf;
#pragma unroll
                for (int j = 0; j < F_MID; j++) v += tile[n][j] * w2c[j];
                acc += fmaxf(v, 0.f);
            }
        }
    }
    atomicAdd(&out[g * F_OUT + f], acc * (1.0f / (float)K_TOP));
}

extern "C" void kernel_launch(void* const* d_in, const int* in_sizes, int n_in,
                              void* d_out, int out_size, void* d_ws, size_t ws_size,
                              hipStream_t stream) {
    const float* x      = (const float*)d_in[0];
    const int*   ei     = (const int*)d_in[1];
    const float* W1     = (const float*)d_in[3];
    const float* b1     = (const float*)d_in[4];
    const float* w_rel  = (const float*)d_in[5];
    const float* b_rel  = (const float*)d_in[6];
    const float* w_root = (const float*)d_in[7];
    const float* W2     = (const float*)d_in[8];
    const float* b2     = (const float*)d_in[9];
    float* out = (float*)d_out;

    char* ws = (char*)d_ws;
    size_t o = 0;
    int*   csr   = (int*)(ws + o);   o += (size_t)N_NODES * CAP * sizeof(int);
    int*   cnt   = (int*)(ws + o);   o += (size_t)N_NODES * sizeof(int);
    float* xw1   = (float*)(ws + o); o += (size_t)N_NODES * F_MID * sizeof(float);
    float* h     = (float*)(ws + o); o += (size_t)N_NODES * F_MID * sizeof(float);
    float* pre   = (float*)(ws + o); o += (size_t)N_NODES * F_MID * sizeof(float);
    float* dis1  = (float*)(ws + o); o += (size_t)N_NODES * sizeof(float);
    float* score = (float*)(ws + o); o += (size_t)N_NODES * sizeof(float);
    float* maskv = (float*)(ws + o); o += (size_t)N_NODES * sizeof(float);
    float* sg    = (float*)(ws + o); o += (size_t)N_NODES * sizeof(float);
    float* dis2  = (float*)(ws + o); o += (size_t)N_NODES * sizeof(float);
    float* wsrcv = (float*)(ws + o); o += (size_t)N_NODES * sizeof(float);

    k_zero<<<(N_NODES + 255) / 256, 256, 0, stream>>>(cnt, out);
    k_build_csr<<<N_EDGES / 256, 256, 0, stream>>>(ei, cnt, csr);
    k_gemm1<<<N_NODES / 16, 256, 0, stream>>>(x, W1, xw1);
    k_deg1<<<(N_NODES + 255) / 256, 256, 0, stream>>>(cnt, dis1);
    k_agg1<<<N_NODES / 16, 256, 0, stream>>>(xw1, dis1, cnt, csr, b1, h);
    k_score<<<N_NODES / 16, 256, 0, stream>>>(h, cnt, csr, w_rel, w_root, b_rel, score);
    k_topk<<<NG, 256, 0, stream>>>(score, maskv, sg);
    k_deg2<<<N_NODES / 16, 256, 0, stream>>>(maskv, sg, cnt, csr, dis2, wsrcv);
    k_pre<<<N_NODES / 16, 256, 0, stream>>>(h, sg, dis2, wsrcv, cnt, csr, pre);
    k_final<<<NG * NCHUNK, 256, 0, stream>>>(pre, maskv, W2, b2, out);
}

// Round 2
// 443.363 us; speedup vs baseline: 1.2438x; 1.2438x over previous
//
#include <hip/hip_runtime.h>
#include <math.h>

#define N_NODES 100000
#define NG 100
#define N_PER 1000
#define N_EDGES 3200000
#define EPG (N_EDGES / NG)   // 32000 edges per graph, graph-contiguous
#define K_TOP 800
#define F_IN 128
#define F_MID 16
#define F_OUT 256

// ============ per-graph compact CSR (u16 local src), counts, dis1, zero out ============
// Edges of graph g occupy e in [g*EPG, (g+1)*EPG); src/dst in [g*1000, (g+1)*1000).
__global__ __launch_bounds__(1024) void k_csr(const int* __restrict__ ei,
                                              unsigned short* __restrict__ csr,
                                              int* __restrict__ cnt,
                                              int* __restrict__ rowstart,
                                              float* __restrict__ dis1,
                                              float* __restrict__ out) {
    __shared__ int cnts[1024];
    __shared__ int offs[1024];
    __shared__ int cur[1024];
    int g = blockIdx.x, t = threadIdx.x;
    int ebase = g * EPG;
    int nbase = g * N_PER;
    cnts[t] = 0; cur[t] = 0;
    if (t < F_OUT) out[g * F_OUT + t] = 0.f;   // zero the output row (ws/out poisoned)
    __syncthreads();
    const int* __restrict__ dstp = ei + N_EDGES + ebase;
    const int* __restrict__ srcp = ei + ebase;
    // pass 1: degree count in LDS
    for (int e = t; e < EPG; e += 1024) {
        int d = dstp[e] - nbase;
        atomicAdd(&cnts[d], 1);
    }
    __syncthreads();
    // inclusive Hillis-Steele scan over 1024 (pad zeros), then exclusive
    int myc = (t < N_PER) ? cnts[t] : 0;
    offs[t] = myc;
    __syncthreads();
    for (int dd = 1; dd < 1024; dd <<= 1) {
        int v = (t >= dd) ? offs[t - dd] : 0;
        __syncthreads();
        offs[t] += v;
        __syncthreads();
    }
    int exc = offs[t] - myc;
    __syncthreads();
    offs[t] = exc;   // exclusive prefix
    if (t < N_PER) {
        cnt[nbase + t] = myc;
        rowstart[nbase + t] = ebase + exc;
        dis1[nbase + t] = rsqrtf((float)myc + 1.0f);
    }
    __syncthreads();
    // pass 2: dense scatter, u16 local src
    for (int e = t; e < EPG; e += 1024) {
        int d = dstp[e] - nbase;
        int s = srcp[e] - nbase;
        int p = offs[d] + atomicAdd(&cur[d], 1);
        csr[ebase + p] = (unsigned short)s;
    }
}

// ============ xw1 = x @ W1 (100000x128 @ 128x16) ============
__global__ void k_gemm1(const float* __restrict__ x, const float* __restrict__ W1,
                        float* __restrict__ xw1) {
    __shared__ float xs[16 * 132];
    __shared__ float ws[128 * 16];
    int t = threadIdx.x;
    int n0 = blockIdx.x * 16;
    const float* xp = x + (size_t)n0 * F_IN;
    for (int i = t; i < 16 * F_IN; i += 256) {
        int n = i / F_IN, k = i % F_IN;
        xs[n * 132 + k] = xp[i];
    }
    for (int i = t; i < F_IN * F_MID; i += 256) ws[i] = W1[i];
    __syncthreads();
    int node = t >> 4, j = t & 15;
    const float* xr = xs + node * 132;
    float acc = 0.f;
#pragma unroll 16
    for (int k = 0; k < F_IN; k++) acc += xr[k] * ws[k * F_MID + j];
    xw1[(size_t)(n0 + node) * F_MID + j] = acc;
}

// ============ conv1 aggregation + bias + relu -> h ============
__global__ void k_agg1(const float* __restrict__ xw1, const float* __restrict__ dis1,
                       const int* __restrict__ cnt, const int* __restrict__ rowstart,
                       const unsigned short* __restrict__ csr,
                       const float* __restrict__ b1, float* __restrict__ h) {
    int gid = blockIdx.x * 16 + (threadIdx.x >> 4);
    int j = threadIdx.x & 15;
    int c = cnt[gid];
    int base = rowstart[gid];
    int gb = gid - (gid % N_PER);
    float sum = 0.f;
    for (int k = 0; k < c; k++) {
        int s = gb + (int)csr[base + k];
        sum += xw1[(size_t)s * F_MID + j] * dis1[s];
    }
    float di = dis1[gid];
    float v = fmaf(sum, di, fmaf(xw1[(size_t)gid * F_MID + j], di * di, b1[j]));
    h[(size_t)gid * F_MID + j] = fmaxf(v, 0.f);
}

// ============ SAGPool score ============
__global__ void k_score(const float* __restrict__ h, const int* __restrict__ cnt,
                        const int* __restrict__ rowstart, const unsigned short* __restrict__ csr,
                        const float* __restrict__ w_rel, const float* __restrict__ w_root,
                        const float* __restrict__ b_rel, float* __restrict__ score) {
    int gid = blockIdx.x * 16 + (threadIdx.x >> 4);
    int j = threadIdx.x & 15;
    int c = cnt[gid];
    int base = rowstart[gid];
    int gb = gid - (gid % N_PER);
    float aggj = 0.f;
    for (int k = 0; k < c; k++) {
        int s = gb + (int)csr[base + k];
        aggj += h[(size_t)s * F_MID + j];
    }
    float val = aggj * w_rel[j] + h[(size_t)gid * F_MID + j] * w_root[j];
    for (int o = 8; o > 0; o >>= 1) val += __shfl_xor(val, o, 16);
    if (j == 0) score[gid] = tanhf(val + b_rel[0]);
}

// ============ per-graph top-K mask + gated score + deg2/dis2/wsrc (merged) ============
__global__ __launch_bounds__(1024) void k_topk2(const float* __restrict__ score,
                                                const int* __restrict__ cnt,
                                                const int* __restrict__ rowstart,
                                                const unsigned short* __restrict__ csr,
                                                float* __restrict__ maskv,
                                                float* __restrict__ sgv,
                                                float* __restrict__ dis2,
                                                float* __restrict__ wsrcv) {
    __shared__ float s[N_PER];
    __shared__ float ss[1024];
    __shared__ float m[N_PER];
    __shared__ float sgl[N_PER];
    __shared__ int cnt_gt;
    int g = blockIdx.x, t = threadIdx.x;
    int nbase = g * N_PER;
    const float* sp = score + nbase;
    if (t < N_PER) { float v = sp[t]; s[t] = v; ss[t] = v; }
    else ss[t] = -1e30f;
    if (t == 0) cnt_gt = 0;
    __syncthreads();
    // bitonic sort ascending over 1024 (one element per thread slot)
    for (int k2 = 2; k2 <= 1024; k2 <<= 1) {
        for (int j2 = k2 >> 1; j2 > 0; j2 >>= 1) {
            int ixj = t ^ j2;
            if (ixj > t) {
                float a = ss[t], b = ss[ixj];
                bool asc = ((t & k2) == 0);
                if ((a > b) == asc) { ss[t] = b; ss[ixj] = a; }
            }
            __syncthreads();
        }
    }
    float thr = ss[1024 - K_TOP];   // K-th largest
    unsigned long long bal = __ballot(t < N_PER && s[t] > thr);
    if ((t & 63) == 0) atomicAdd(&cnt_gt, (int)__popcll(bal));
    __syncthreads();
    int need = K_TOP - cnt_gt;   // ties to accept, lowest index first (top_k semantics)
    if (t < N_PER) {
        float v = s[t];
        float mm;
        if (v > thr) mm = 1.f;
        else if (v < thr) mm = 0.f;
        else {
            int r = 0;
            for (int l = 0; l < t; l++) if (s[l] == thr) r++;
            mm = (r < need) ? 1.f : 0.f;
        }
        m[t] = mm;
        sgl[t] = v * mm;
        maskv[nbase + t] = mm;
        sgv[nbase + t] = v * mm;
    }
    __syncthreads();
    // deg2: mask-gather from LDS; dis2 + wsrc
    int grp = t >> 4, j = t & 15;
    for (int node = grp; node < N_PER; node += 64) {
        int c = cnt[nbase + node];
        int base = rowstart[nbase + node];
        float sum = 0.f;
        for (int k = j; k < c; k += 16) sum += m[csr[base + k]];
        for (int o = 8; o > 0; o >>= 1) sum += __shfl_xor(sum, o, 16);
        if (j == 0) {
            float d2 = m[node] * (sum + 1.f);
            float di = (d2 > 0.f) ? rsqrtf(d2) : 0.f;
            dis2[nbase + node] = di;
            wsrcv[nbase + node] = sgl[node] * di;
        }
    }
}

// ============ conv2 pre-GEMM aggregation in F_MID dims ============
__global__ void k_pre(const float* __restrict__ h, const float* __restrict__ sgv,
                      const float* __restrict__ dis2, const float* __restrict__ wsrcv,
                      const int* __restrict__ cnt, const int* __restrict__ rowstart,
                      const unsigned short* __restrict__ csr, float* __restrict__ pre) {
    int gid = blockIdx.x * 16 + (threadIdx.x >> 4);
    int j = threadIdx.x & 15;
    float di = dis2[gid];
    if (di == 0.f) {   // masked-out node (group-uniform)
        pre[(size_t)gid * F_MID + j] = 0.f;
        return;
    }
    int c = cnt[gid];
    int base = rowstart[gid];
    int gb = gid - (gid % N_PER);
    float sum = 0.f;
    for (int k = 0; k < c; k++) {
        int s = gb + (int)csr[base + k];
        sum += h[(size_t)s * F_MID + j] * wsrcv[s];
    }
    float v = fmaf(sum, di, h[(size_t)gid * F_MID + j] * sgv[gid] * di * di);
    pre[(size_t)gid * F_MID + j] = v;
}

// ============ fused GEMM2 + relu + masked mean-pool ============
#define NCHUNK 4
#define CH_NODES (N_PER / NCHUNK)   // 250
__global__ void k_final(const float* __restrict__ pre, const float* __restrict__ maskv,
                        const float* __restrict__ W2, const float* __restrict__ b2,
                        float* __restrict__ out) {
    int g = blockIdx.x / NCHUNK;
    int ch = blockIdx.x % NCHUNK;
    int f = threadIdx.x;
    float w2c[F_MID];
#pragma unroll
    for (int j = 0; j < F_MID; j++) w2c[j] = W2[j * F_OUT + f];
    float bf = b2[f];
    __shared__ float tile[32][F_MID];
    __shared__ float mv[32];
    float acc = 0.f;
    int nbeg = g * N_PER + ch * CH_NODES;
    for (int t0 = 0; t0 < CH_NODES; t0 += 32) {
        int nn = min(32, CH_NODES - t0);
        __syncthreads();
        for (int i = threadIdx.x; i < nn * F_MID; i += 256)
            tile[i / F_MID][i % F_MID] = pre[(size_t)(nbeg + t0) * F_MID + i];
        for (int i = threadIdx.x; i < nn; i += 256) mv[i] = maskv[nbeg + t0 + i];
        __syncthreads();
        for (int n = 0; n < nn; n++) {
            if (mv[n] != 0.f) {
                float v = bf;
#pragma unroll
                for (int j = 0; j < F_MID; j++) v += tile[n][j] * w2c[j];
                acc += fmaxf(v, 0.f);
            }
        }
    }
    atomicAdd(&out[g * F_OUT + f], acc * (1.0f / (float)K_TOP));
}

extern "C" void kernel_launch(void* const* d_in, const int* in_sizes, int n_in,
                              void* d_out, int out_size, void* d_ws, size_t ws_size,
                              hipStream_t stream) {
    const float* x      = (const float*)d_in[0];
    const int*   ei     = (const int*)d_in[1];
    const float* W1     = (const float*)d_in[3];
    const float* b1     = (const float*)d_in[4];
    const float* w_rel  = (const float*)d_in[5];
    const float* b_rel  = (const float*)d_in[6];
    const float* w_root = (const float*)d_in[7];
    const float* W2     = (const float*)d_in[8];
    const float* b2     = (const float*)d_in[9];
    float* out = (float*)d_out;

    char* ws = (char*)d_ws;
    size_t o = 0;
    unsigned short* csr = (unsigned short*)(ws + o); o += (size_t)N_EDGES * sizeof(unsigned short);
    int*   cnt      = (int*)(ws + o);   o += (size_t)N_NODES * sizeof(int);
    int*   rowstart = (int*)(ws + o);   o += (size_t)N_NODES * sizeof(int);
    float* xw1   = (float*)(ws + o); o += (size_t)N_NODES * F_MID * sizeof(float);
    float* h     = (float*)(ws + o); o += (size_t)N_NODES * F_MID * sizeof(float);
    float* pre   = (float*)(ws + o); o += (size_t)N_NODES * F_MID * sizeof(float);
    float* dis1  = (float*)(ws + o); o += (size_t)N_NODES * sizeof(float);
    float* score = (float*)(ws + o); o += (size_t)N_NODES * sizeof(float);
    float* maskv = (float*)(ws + o); o += (size_t)N_NODES * sizeof(float);
    float* sgv   = (float*)(ws + o); o += (size_t)N_NODES * sizeof(float);
    float* dis2  = (float*)(ws + o); o += (size_t)N_NODES * sizeof(float);
    float* wsrcv = (float*)(ws + o); o += (size_t)N_NODES * sizeof(float);

    k_csr<<<NG, 1024, 0, stream>>>(ei, csr, cnt, rowstart, dis1, out);
    k_gemm1<<<N_NODES / 16, 256, 0, stream>>>(x, W1, xw1);
    k_agg1<<<N_NODES / 16, 256, 0, stream>>>(xw1, dis1, cnt, rowstart, csr, b1, h);
    k_score<<<N_NODES / 16, 256, 0, stream>>>(h, cnt, rowstart, csr, w_rel, w_root, b_rel, score);
    k_topk2<<<NG, 1024, 0, stream>>>(score, cnt, rowstart, csr, maskv, sgv, dis2, wsrcv);
    k_pre<<<N_NODES / 16, 256, 0, stream>>>(h, sgv, dis2, wsrcv, cnt, rowstart, csr, pre);
    k_final<<<NG * NCHUNK, 256, 0, stream>>>(pre, maskv, W2, b2, out);
}

// Round 3
// 335.656 us; speedup vs baseline: 1.6429x; 1.3209x over previous
//
#include <hip/hip_runtime.h>
#include <math.h>

#define N_NODES 100000
#define NG 100
#define N_PER 1000
#define N_EDGES 3200000
#define EPG 32000
#define EPG4 8000
#define K_TOP 800
#define F_IN 128
#define F_MID 16
#define F_OUT 256

typedef __attribute__((ext_vector_type(8))) short short8;
typedef __attribute__((ext_vector_type(4))) float floatx4;

__device__ __forceinline__ unsigned short f2bf(float x) {
    union { float f; unsigned int u; } c; c.f = x;
    unsigned int u = c.u;
    u = u + 0x7FFF + ((u >> 16) & 1);   // round-to-nearest-even
    return (unsigned short)(u >> 16);
}

// ============ xw1 = x @ W1 (100000x128 @ 128x16), full-machine parallel ============
__global__ void k_gemm1(const float* __restrict__ x, const float* __restrict__ W1,
                        float* __restrict__ xw1) {
    __shared__ float xs[16 * 132];
    __shared__ float ws[128 * 16];
    int t = threadIdx.x;
    int n0 = blockIdx.x * 16;
    const float* xp = x + (size_t)n0 * F_IN;
    for (int i = t; i < 16 * F_IN; i += 256) {
        int n = i / F_IN, k = i % F_IN;
        xs[n * 132 + k] = xp[i];
    }
    for (int i = t; i < F_IN * F_MID; i += 256) ws[i] = W1[i];
    __syncthreads();
    int node = t >> 4, j = t & 15;
    const float* xr = xs + node * 132;
    float acc = 0.f;
#pragma unroll 16
    for (int k = 0; k < F_IN; k++) acc += xr[k] * ws[k * F_MID + j];
    xw1[(size_t)(n0 + node) * F_MID + j] = acc;
}

// ============ everything else: one block per graph, all state in LDS ============
__global__ __launch_bounds__(1024) void k_mega(
    const int* __restrict__ ei, const float* __restrict__ xw1,
    unsigned short* __restrict__ csr,
    const float* __restrict__ b1, const float* __restrict__ w_rel,
    const float* __restrict__ b_rel, const float* __restrict__ w_root,
    const float* __restrict__ W2, const float* __restrict__ b2,
    float* __restrict__ out)
{
    __shared__ float feat[N_PER * F_MID];          // 64000 B: xw1 -> h -> pre (in place)
    __shared__ unsigned short fbf[N_PER * F_MID];  // 32000 B: bf16 copy of pre
    __shared__ int cnts[N_PER];                    // 4000
    __shared__ int offs[1024];                     // 4096 (exclusive prefix = row starts)
    __shared__ int cur[N_PER];                     // 4000
    __shared__ float dis1[N_PER];                  // 4000
    __shared__ float sc[N_PER];                    // 4000
    __shared__ float ssrt[1024];                   // 4096 (bitonic sort buffer)
    __shared__ float msk[N_PER];                   // 4000
    __shared__ float dis2[N_PER];                  // 4000
    __shared__ float wsrc[N_PER];                  // 4000
    __shared__ unsigned short w2t[F_OUT * F_MID];  // 8192 (W2^T in bf16)
    __shared__ int cnt_gt;                         // total ~140.4 KB < 160 KB

    int t = threadIdx.x, g = blockIdx.x;
    int nbase = g * N_PER, ebase = g * EPG;
    int grp = t >> 4, j = t & 15;
    unsigned short* cg = csr + (size_t)ebase;

    // ---- init + W2^T bf16 staging ----
    if (t < N_PER) { cnts[t] = 0; cur[t] = 0; }
    if (t == 0) cnt_gt = 0;
    for (int i = t; i < F_OUT * F_MID; i += 1024) {
        int f = i >> 4, jj = i & 15;
        w2t[i] = f2bf(W2[jj * F_OUT + f]);
    }
    __syncthreads();

    // ---- CSR pass 1: degree count (int4 edge loads for ILP) ----
    const int4* dst4 = (const int4*)(ei + N_EDGES + ebase);
    for (int i = t; i < EPG4; i += 1024) {
        int4 d = dst4[i];
        atomicAdd(&cnts[d.x - nbase], 1);
        atomicAdd(&cnts[d.y - nbase], 1);
        atomicAdd(&cnts[d.z - nbase], 1);
        atomicAdd(&cnts[d.w - nbase], 1);
    }
    __syncthreads();

    // ---- scan (Hillis-Steele over 1024) -> exclusive row offsets ----
    int myc = (t < N_PER) ? cnts[t] : 0;
    offs[t] = myc;
    __syncthreads();
    for (int dd = 1; dd < 1024; dd <<= 1) {
        int v = (t >= dd) ? offs[t - dd] : 0;
        __syncthreads();
        offs[t] += v;
        __syncthreads();
    }
    int exc = offs[t] - myc;
    __syncthreads();
    offs[t] = exc;
    if (t < N_PER) dis1[t] = rsqrtf((float)myc + 1.0f);
    __syncthreads();

    // ---- CSR pass 2: dense scatter, u16 local src ----
    const int4* src4 = (const int4*)(ei + ebase);
    for (int i = t; i < EPG4; i += 1024) {
        int4 s4 = src4[i];
        int4 d4 = dst4[i];
        int dl, p;
        dl = d4.x - nbase; p = offs[dl] + atomicAdd(&cur[dl], 1); cg[p] = (unsigned short)(s4.x - nbase);
        dl = d4.y - nbase; p = offs[dl] + atomicAdd(&cur[dl], 1); cg[p] = (unsigned short)(s4.y - nbase);
        dl = d4.z - nbase; p = offs[dl] + atomicAdd(&cur[dl], 1); cg[p] = (unsigned short)(s4.z - nbase);
        dl = d4.w - nbase; p = offs[dl] + atomicAdd(&cur[dl], 1); cg[p] = (unsigned short)(s4.w - nbase);
    }
    __syncthreads();

    // ---- stage xw1 window into LDS (float4 coalesced) ----
    {
        const float4* xsrc = (const float4*)(xw1 + (size_t)nbase * F_MID);
        float4* fdst = (float4*)feat;
        for (int i = t; i < N_PER * 4; i += 1024) fdst[i] = xsrc[i];
    }
    __syncthreads();

    float b1j = b1[j], wrelj = w_rel[j], wrootj = w_root[j], brel = b_rel[0];

    // ---- conv1 aggregation + relu: h into registers, then overwrite feat ----
    float hreg[16];
#pragma unroll
    for (int w = 0; w < 16; w++) {
        int n = grp + 64 * w;
        if (n < N_PER) {
            int c = cnts[n], base = offs[n];
            const unsigned short* cp = cg + base;
            float sum = 0.f;
            for (int k = 0; k < c; k++) {
                int s = cp[k];
                sum += feat[s * F_MID + j] * dis1[s];
            }
            float di = dis1[n];
            hreg[w] = fmaxf(fmaf(sum, di, fmaf(feat[n * F_MID + j], di * di, b1j)), 0.f);
        }
    }
    __syncthreads();
#pragma unroll
    for (int w = 0; w < 16; w++) {
        int n = grp + 64 * w;
        if (n < N_PER) feat[n * F_MID + j] = hreg[w];
    }
    __syncthreads();

    // ---- SAGPool score ----
#pragma unroll
    for (int w = 0; w < 16; w++) {
        int n = grp + 64 * w;
        if (n < N_PER) {
            int c = cnts[n], base = offs[n];
            const unsigned short* cp = cg + base;
            float aggj = 0.f;
            for (int k = 0; k < c; k++) aggj += feat[cp[k] * F_MID + j];
            float val = aggj * wrelj + feat[n * F_MID + j] * wrootj;
            for (int o = 8; o > 0; o >>= 1) val += __shfl_xor(val, o, 16);
            if (j == 0) sc[n] = tanhf(val + brel);
        }
    }
    __syncthreads();

    // ---- bitonic top-K -> threshold + mask (ties: lowest index) ----
    ssrt[t] = (t < N_PER) ? sc[t] : -1e30f;
    __syncthreads();
    for (int k2 = 2; k2 <= 1024; k2 <<= 1) {
        for (int j2 = k2 >> 1; j2 > 0; j2 >>= 1) {
            int ixj = t ^ j2;
            if (ixj > t) {
                float a = ssrt[t], b = ssrt[ixj];
                bool asc = ((t & k2) == 0);
                if ((a > b) == asc) { ssrt[t] = b; ssrt[ixj] = a; }
            }
            __syncthreads();
        }
    }
    float thr = ssrt[1024 - K_TOP];
    bool pred = (t < N_PER) && (sc[t] > thr);
    unsigned long long bal = __ballot(pred);
    if ((t & 63) == 0) atomicAdd(&cnt_gt, (int)__popcll(bal));
    __syncthreads();
    int need = K_TOP - cnt_gt;
    if (t < N_PER) {
        float v = sc[t];
        float mm;
        if (v > thr) mm = 1.f;
        else if (v < thr) mm = 0.f;
        else {
            int r = 0;
            for (int l = 0; l < t; l++) if (sc[l] == thr) r++;
            mm = (r < need) ? 1.f : 0.f;
        }
        msk[t] = mm;
    }
    __syncthreads();

    // ---- deg2 / dis2 / wsrc (mask gather from LDS) ----
#pragma unroll
    for (int w = 0; w < 16; w++) {
        int n = grp + 64 * w;
        if (n < N_PER) {
            int c = cnts[n], base = offs[n];
            const unsigned short* cp = cg + base;
            float sm = 0.f;
            for (int k = j; k < c; k += 16) sm += msk[cp[k]];
            for (int o = 8; o > 0; o >>= 1) sm += __shfl_xor(sm, o, 16);
            if (j == 0) {
                float d2 = msk[n] * (sm + 1.f);
                float di = (d2 > 0.f) ? rsqrtf(d2) : 0.f;
                dis2[n] = di;
                wsrc[n] = sc[n] * msk[n] * di;
            }
        }
    }
    __syncthreads();

    // ---- conv2 pre-GEMM aggregation (F_MID dims): pre into registers ----
    float preg[16];
#pragma unroll
    for (int w = 0; w < 16; w++) {
        int n = grp + 64 * w;
        if (n < N_PER) {
            float di = dis2[n];
            float pv = 0.f;
            if (di != 0.f) {
                int c = cnts[n], base = offs[n];
                const unsigned short* cp = cg + base;
                float sum = 0.f;
                for (int k = 0; k < c; k++) {
                    int s = cp[k];
                    sum += feat[s * F_MID + j] * wsrc[s];
                }
                pv = fmaf(sum, di, feat[n * F_MID + j] * sc[n] * msk[n] * di * di);
            }
            preg[w] = pv;
        }
    }
    __syncthreads();
#pragma unroll
    for (int w = 0; w < 16; w++) {
        int n = grp + 64 * w;
        if (n < N_PER) feat[n * F_MID + j] = preg[w];
    }
    __syncthreads();

    // ---- pre -> bf16 (mask already decided; rounding err ~3e-5) ----
    for (int i = t; i < N_PER * F_MID; i += 1024) fbf[i] = f2bf(feat[i]);
    __syncthreads();

    // ---- final: (800x16) @ (16x256) via mfma_f32_16x16x32_bf16 + relu + masked mean-pool ----
    {
        int wave = t >> 6, lane = t & 63;
        int q = lane >> 4, fl = lane & 15;
        int fglob = wave * 16 + fl;
        float b2f = b2[fglob];
        short8 bfrag = {0, 0, 0, 0, 0, 0, 0, 0};
        if (q < 2) bfrag = *(const short8*)(w2t + fglob * F_MID + q * 8);
        floatx4 zero = {0.f, 0.f, 0.f, 0.f};
        float acc = 0.f;
        for (int tile = 0; tile < 63; tile++) {
            short8 afrag = {0, 0, 0, 0, 0, 0, 0, 0};
            int na = tile * 16 + fl;   // A-row (node) index: m = lane&15
            if (q < 2 && na < N_PER)
                afrag = *(const short8*)(fbf + na * F_MID + q * 8);
            floatx4 d = __builtin_amdgcn_mfma_f32_16x16x32_bf16(afrag, bfrag, zero, 0, 0, 0);
#pragma unroll
            for (int r = 0; r < 4; r++) {
                int nd = tile * 16 + q * 4 + r;   // C-row = quad*4 + reg
                if (nd < N_PER) acc += msk[nd] * fmaxf(d[r] + b2f, 0.f);
            }
        }
        acc += __shfl_xor(acc, 16);
        acc += __shfl_xor(acc, 32);
        if (lane < 16) out[g * F_OUT + fglob] = acc * (1.0f / (float)K_TOP);
    }
}

extern "C" void kernel_launch(void* const* d_in, const int* in_sizes, int n_in,
                              void* d_out, int out_size, void* d_ws, size_t ws_size,
                              hipStream_t stream) {
    const float* x      = (const float*)d_in[0];
    const int*   ei     = (const int*)d_in[1];
    const float* W1     = (const float*)d_in[3];
    const float* b1     = (const float*)d_in[4];
    const float* w_rel  = (const float*)d_in[5];
    const float* b_rel  = (const float*)d_in[6];
    const float* w_root = (const float*)d_in[7];
    const float* W2     = (const float*)d_in[8];
    const float* b2     = (const float*)d_in[9];
    float* out = (float*)d_out;

    char* ws = (char*)d_ws;
    size_t o = 0;
    unsigned short* csr = (unsigned short*)(ws + o); o += (size_t)N_EDGES * sizeof(unsigned short);
    float* xw1 = (float*)(ws + o); o += (size_t)N_NODES * F_MID * sizeof(float);

    k_gemm1<<<N_NODES / 16, 256, 0, stream>>>(x, W1, xw1);
    k_mega<<<NG, 1024, 0, stream>>>(ei, xw1, csr, b1, w_rel, b_rel, w_root, W2, b2, out);
}

// Round 4
// 243.848 us; speedup vs baseline: 2.2614x; 1.3765x over previous
//
#include <hip/hip_runtime.h>
#include <math.h>

#define N_NODES 100000
#define NG 100
#define N_PER 1000
#define N_EDGES 3200000
#define EPG 32000
#define EPG4 8000
#define EPGP 35008          // padded CSR stride per graph (<= 32000 + 3*1000, mult of 4)
#define K_TOP 800
#define F_IN 128
#define F_MID 16
#define F_OUT 256
#define SENT 1000           // sentinel node index (zero row / zero weight)

typedef __attribute__((ext_vector_type(8))) short short8;
typedef __attribute__((ext_vector_type(4))) float floatx4;

__device__ __forceinline__ unsigned short f2bf(float x) {
    union { float f; unsigned int u; } c; c.f = x;
    unsigned int u = c.u;
    u = u + 0x7FFF + ((u >> 16) & 1);
    return (unsigned short)(u >> 16);
}
__device__ __forceinline__ void add4(float4& a, const float4 b) {
    a.x += b.x; a.y += b.y; a.z += b.z; a.w += b.w;
}
__device__ __forceinline__ void fma4(float4& a, const float4 b, float w) {
    a.x = fmaf(b.x, w, a.x); a.y = fmaf(b.y, w, a.y);
    a.z = fmaf(b.z, w, a.z); a.w = fmaf(b.w, w, a.w);
}

// ============ kernel 1: GEMM1 tiles + CSR-build blocks, overlapped ============
__global__ __launch_bounds__(256) void k_front(const float* __restrict__ x,
    const float* __restrict__ W1, const int* __restrict__ ei,
    unsigned short* __restrict__ csr, int* __restrict__ cntG, int* __restrict__ rsG,
    float* __restrict__ dis1G, float* __restrict__ xw1)
{
    __shared__ __align__(16) char smem[16640];
    int b = blockIdx.x, t = threadIdx.x;
    if (b < NG) {
        // ---------------- CSR build for graph b ----------------
        int g = b;
        int* cnts = (int*)smem;            // 1000 ints
        int* rs   = (int*)(smem + 4000);   // 1000 ints (local row starts, mult of 4)
        int* cur  = (int*)(smem + 8000);   // 1000 ints
        int* sums = (int*)(smem + 12000);  // 256 ints
        for (int i = t; i < N_PER; i += 256) { cnts[i] = 0; cur[i] = 0; }
        __syncthreads();
        int ebase = g * EPG, nbase = g * N_PER;
        const int4* dst4 = (const int4*)(ei + N_EDGES + ebase);
        const int4* src4 = (const int4*)(ei + ebase);
        for (int i = t; i < EPG4; i += 256) {
            int4 d = dst4[i];
            atomicAdd(&cnts[d.x - nbase], 1);
            atomicAdd(&cnts[d.y - nbase], 1);
            atomicAdd(&cnts[d.z - nbase], 1);
            atomicAdd(&cnts[d.w - nbase], 1);
        }
        __syncthreads();
        // thread t owns nodes 4t..4t+3; scan padded counts
        int c[4], cpd[4], pl[4], tot;
        if (t < 250) {
            for (int r = 0; r < 4; r++) { c[r] = cnts[4 * t + r]; cpd[r] = (c[r] + 3) & ~3; }
        } else {
            for (int r = 0; r < 4; r++) { c[r] = 0; cpd[r] = 0; }
        }
        pl[0] = 0;
        for (int r = 1; r < 4; r++) pl[r] = pl[r - 1] + cpd[r - 1];
        tot = pl[3] + cpd[3];
        sums[t] = tot;
        __syncthreads();
        for (int dd = 1; dd < 256; dd <<= 1) {
            int v = (t >= dd) ? sums[t - dd] : 0;
            __syncthreads();
            sums[t] += v;
            __syncthreads();
        }
        int exc = sums[t] - tot;
        unsigned short* cg = csr + (size_t)g * EPGP;
        if (t < 250) {
            for (int r = 0; r < 4; r++) {
                int n = 4 * t + r, base = exc + pl[r];
                rs[n] = base;
                rsG[nbase + n] = base;
                cntG[nbase + n] = c[r];
                dis1G[nbase + n] = rsqrtf((float)c[r] + 1.0f);
                for (int q = c[r]; q < cpd[r]; q++) cg[base + q] = (unsigned short)SENT;
            }
        }
        __syncthreads();
        for (int i = t; i < EPG4; i += 256) {
            int4 s4 = src4[i]; int4 d4 = dst4[i];
            int dl, p;
            dl = d4.x - nbase; p = rs[dl] + atomicAdd(&cur[dl], 1); cg[p] = (unsigned short)(s4.x - nbase);
            dl = d4.y - nbase; p = rs[dl] + atomicAdd(&cur[dl], 1); cg[p] = (unsigned short)(s4.y - nbase);
            dl = d4.z - nbase; p = rs[dl] + atomicAdd(&cur[dl], 1); cg[p] = (unsigned short)(s4.z - nbase);
            dl = d4.w - nbase; p = rs[dl] + atomicAdd(&cur[dl], 1); cg[p] = (unsigned short)(s4.w - nbase);
        }
    } else {
        // ---------------- GEMM1 tile: 16 nodes x (128 -> 16) ----------------
        int tile = b - NG, n0 = tile * 16;
        float* xs = (float*)smem;            // 16*132 floats
        float* ws = (float*)(smem + 8448);   // 128*16 floats
        const float* xp = x + (size_t)n0 * F_IN;
        for (int i = t; i < 16 * F_IN; i += 256) {
            int n = i >> 7, k = i & 127;
            xs[n * 132 + k] = xp[i];
        }
        for (int i = t; i < F_IN * F_MID; i += 256) ws[i] = W1[i];
        __syncthreads();
        int node = t >> 4, j = t & 15;
        const float* xr = xs + node * 132;
        float acc = 0.f;
#pragma unroll 16
        for (int k = 0; k < F_IN; k++) acc += xr[k] * ws[k * F_MID + j];
        xw1[(size_t)(n0 + node) * F_MID + j] = acc;
    }
}

// ============ kernel 2: per-graph phases, CSR prebuilt, ILP-optimized gathers ============
__global__ __launch_bounds__(1024) void k_mega(const unsigned short* __restrict__ csr,
    const int* __restrict__ cntG, const int* __restrict__ rsG,
    const float* __restrict__ dis1G, const float* __restrict__ xw1,
    const float* __restrict__ b1, const float* __restrict__ w_rel,
    const float* __restrict__ b_rel, const float* __restrict__ w_root,
    const float* __restrict__ W2, const float* __restrict__ b2,
    float* __restrict__ out)
{
    __shared__ __align__(16) float feat[(N_PER + 1) * F_MID];     // 64064 B: xw1*dis1 -> h -> pre
    __shared__ __align__(16) unsigned short fbf[N_PER * F_MID];   // 32000 B
    __shared__ __align__(16) unsigned short w2t[F_OUT * F_MID];   // 8192 B
    __shared__ float sc[N_PER];
    __shared__ float msk[N_PER + 1];
    __shared__ float wsrc[N_PER + 1];
    __shared__ float dis2a[N_PER];
    __shared__ float dis1l[N_PER];
    __shared__ int   cntl[N_PER];
    __shared__ int   rsl[N_PER];
    __shared__ float ssrt[1024];
    __shared__ int cnt_gt;

    int t = threadIdx.x, g = blockIdx.x;
    int nbase = g * N_PER;
    const unsigned short* cg = csr + (size_t)g * EPGP;

    if (t < N_PER) { cntl[t] = cntG[nbase + t]; rsl[t] = rsG[nbase + t]; dis1l[t] = dis1G[nbase + t]; }
    if (t == 0) cnt_gt = 0;
    for (int i = t; i < F_OUT * F_MID; i += 1024) {
        int f = i >> 4, jj = i & 15;
        w2t[i] = f2bf(W2[jj * F_OUT + f]);
    }
    __syncthreads();

    // ---- stage feat = xw1 * dis1; zero sentinel row ----
    {
        const float4* xs = (const float4*)(xw1 + (size_t)nbase * F_MID);
        float4* fd = (float4*)feat;
        for (int i = t; i < N_PER * 4; i += 1024) {
            float4 v = xs[i];
            float d = dis1l[i >> 2];
            v.x *= d; v.y *= d; v.z *= d; v.w *= d;
            fd[i] = v;
        }
        if (t < 4) { float4 z = {0.f, 0.f, 0.f, 0.f}; fd[N_PER * 4 + t] = z; }
    }
    __syncthreads();

    int grp = t >> 2, l = t & 3;   // 256 groups of 4 lanes; lane owns 4 channels
    float4 b14 = *(const float4*)(b1 + 4 * l);
    float4 wr4 = *(const float4*)(w_rel + 4 * l);
    float4 wo4 = *(const float4*)(w_root + 4 * l);
    float brel = b_rel[0];

    // ---- conv1 aggregation + relu ----
    float4 hreg[4];
#pragma unroll
    for (int rr = 0; rr < 4; rr++) {
        int n = grp + 256 * rr;
        if (n < N_PER) {
            int c4 = (cntl[n] + 3) & ~3;
            const unsigned short* cp = cg + rsl[n];
            float4 a0 = {0,0,0,0}, a1 = a0, a2 = a0, a3 = a0;
            for (int k = 0; k < c4; k += 4) {
                uint2 wv = *(const uint2*)(cp + k);
                int s0 = wv.x & 0xFFFF, s1 = wv.x >> 16, s2 = wv.y & 0xFFFF, s3 = wv.y >> 16;
                add4(a0, *(const float4*)(feat + s0 * F_MID + 4 * l));
                add4(a1, *(const float4*)(feat + s1 * F_MID + 4 * l));
                add4(a2, *(const float4*)(feat + s2 * F_MID + 4 * l));
                add4(a3, *(const float4*)(feat + s3 * F_MID + 4 * l));
            }
            add4(a0, a1); add4(a2, a3); add4(a0, a2);
            float4 sf = *(const float4*)(feat + n * F_MID + 4 * l);
            float di = dis1l[n];
            float4 hv;
            hv.x = fmaxf(fmaf(di, a0.x + sf.x, b14.x), 0.f);
            hv.y = fmaxf(fmaf(di, a0.y + sf.y, b14.y), 0.f);
            hv.z = fmaxf(fmaf(di, a0.z + sf.z, b14.z), 0.f);
            hv.w = fmaxf(fmaf(di, a0.w + sf.w, b14.w), 0.f);
            hreg[rr] = hv;
        }
    }
    __syncthreads();
#pragma unroll
    for (int rr = 0; rr < 4; rr++) {
        int n = grp + 256 * rr;
        if (n < N_PER) *(float4*)(feat + n * F_MID + 4 * l) = hreg[rr];
    }
    __syncthreads();

    // ---- SAGPool score ----
#pragma unroll
    for (int rr = 0; rr < 4; rr++) {
        int n = grp + 256 * rr;
        if (n < N_PER) {
            int c4 = (cntl[n] + 3) & ~3;
            const unsigned short* cp = cg + rsl[n];
            float4 a0 = {0,0,0,0}, a1 = a0, a2 = a0, a3 = a0;
            for (int k = 0; k < c4; k += 4) {
                uint2 wv = *(const uint2*)(cp + k);
                int s0 = wv.x & 0xFFFF, s1 = wv.x >> 16, s2 = wv.y & 0xFFFF, s3 = wv.y >> 16;
                add4(a0, *(const float4*)(feat + s0 * F_MID + 4 * l));
                add4(a1, *(const float4*)(feat + s1 * F_MID + 4 * l));
                add4(a2, *(const float4*)(feat + s2 * F_MID + 4 * l));
                add4(a3, *(const float4*)(feat + s3 * F_MID + 4 * l));
            }
            add4(a0, a1); add4(a2, a3); add4(a0, a2);
            float4 sf = *(const float4*)(feat + n * F_MID + 4 * l);
            float val = a0.x * wr4.x + a0.y * wr4.y + a0.z * wr4.z + a0.w * wr4.w
                      + sf.x * wo4.x + sf.y * wo4.y + sf.z * wo4.z + sf.w * wo4.w;
            val += __shfl_xor(val, 1);
            val += __shfl_xor(val, 2);
            if (l == 0) sc[n] = tanhf(val + brel);
        }
    }
    __syncthreads();

    // ---- bitonic sort (barriers only for cross-wave stages) ----
    ssrt[t] = (t < N_PER) ? sc[t] : -1e30f;
    __syncthreads();
    for (int k2 = 2; k2 <= 1024; k2 <<= 1) {
        for (int j2 = k2 >> 1; j2 > 0; j2 >>= 1) {
            if (j2 >= 32) __syncthreads();   // j2<=16 pairs stay inside one wave (in-order LDS)
            int ixj = t ^ j2;
            if (ixj > t) {
                float a = ssrt[t], b = ssrt[ixj];
                bool asc = ((t & k2) == 0);
                if ((a > b) == asc) { ssrt[t] = b; ssrt[ixj] = a; }
            }
        }
    }
    __syncthreads();

    float thr = ssrt[1024 - K_TOP];
    bool pred = (t < N_PER) && (sc[t] > thr);
    unsigned long long bal = __ballot(pred);
    if ((t & 63) == 0) atomicAdd(&cnt_gt, (int)__popcll(bal));
    __syncthreads();
    int need = K_TOP - cnt_gt;
    if (t < N_PER) {
        float v = sc[t];
        float mm;
        if (v > thr) mm = 1.f;
        else if (v < thr) mm = 0.f;
        else {
            int r = 0;
            for (int q = 0; q < t; q++) if (sc[q] == thr) r++;
            mm = (r < need) ? 1.f : 0.f;
        }
        msk[t] = mm;
    }
    if (t == N_PER) { msk[SENT] = 0.f; wsrc[SENT] = 0.f; }
    __syncthreads();

    // ---- deg2 / dis2 / wsrc ----
#pragma unroll
    for (int rr = 0; rr < 4; rr++) {
        int n = grp + 256 * rr;
        if (n < N_PER) {
            int c4 = (cntl[n] + 3) & ~3;
            const unsigned short* cp = cg + rsl[n];
            float sm = 0.f;
            for (int k = 0; k < c4; k += 4) {
                uint2 wv = *(const uint2*)(cp + k);
                int s = (l == 0) ? (int)(wv.x & 0xFFFF) : (l == 1) ? (int)(wv.x >> 16)
                      : (l == 2) ? (int)(wv.y & 0xFFFF) : (int)(wv.y >> 16);
                sm += msk[s];
            }
            sm += __shfl_xor(sm, 1);
            sm += __shfl_xor(sm, 2);
            if (l == 0) {
                float d2 = msk[n] * (sm + 1.f);
                float di = (d2 > 0.f) ? rsqrtf(d2) : 0.f;
                dis2a[n] = di;
                wsrc[n] = sc[n] * msk[n] * di;
            }
        }
    }
    __syncthreads();

    // ---- conv2 pre-GEMM aggregation ----
    float4 preg[4];
#pragma unroll
    for (int rr = 0; rr < 4; rr++) {
        int n = grp + 256 * rr;
        if (n < N_PER) {
            float di = dis2a[n];
            float4 pv = {0,0,0,0};
            if (di != 0.f) {
                int c4 = (cntl[n] + 3) & ~3;
                const unsigned short* cp = cg + rsl[n];
                float4 a0 = {0,0,0,0}, a1 = a0, a2 = a0, a3 = a0;
                for (int k = 0; k < c4; k += 4) {
                    uint2 wv = *(const uint2*)(cp + k);
                    int s0 = wv.x & 0xFFFF, s1 = wv.x >> 16, s2 = wv.y & 0xFFFF, s3 = wv.y >> 16;
                    float ww0 = wsrc[s0], ww1 = wsrc[s1], ww2 = wsrc[s2], ww3 = wsrc[s3];
                    fma4(a0, *(const float4*)(feat + s0 * F_MID + 4 * l), ww0);
                    fma4(a1, *(const float4*)(feat + s1 * F_MID + 4 * l), ww1);
                    fma4(a2, *(const float4*)(feat + s2 * F_MID + 4 * l), ww2);
                    fma4(a3, *(const float4*)(feat + s3 * F_MID + 4 * l), ww3);
                }
                add4(a0, a1); add4(a2, a3); add4(a0, a2);
                float4 sf = *(const float4*)(feat + n * F_MID + 4 * l);
                float wn = wsrc[n];
                pv.x = di * fmaf(sf.x, wn, a0.x);
                pv.y = di * fmaf(sf.y, wn, a0.y);
                pv.z = di * fmaf(sf.z, wn, a0.z);
                pv.w = di * fmaf(sf.w, wn, a0.w);
            }
            preg[rr] = pv;
        }
    }
    __syncthreads();
#pragma unroll
    for (int rr = 0; rr < 4; rr++) {
        int n = grp + 256 * rr;
        if (n < N_PER) *(float4*)(feat + n * F_MID + 4 * l) = preg[rr];
    }
    __syncthreads();

    // ---- pre -> bf16 (packed u32 writes) ----
    for (int i = t; i < N_PER * F_MID / 2; i += 1024) {
        float2 v = *(const float2*)(feat + 2 * i);
        unsigned int pk = (unsigned int)f2bf(v.x) | ((unsigned int)f2bf(v.y) << 16);
        ((unsigned int*)fbf)[i] = pk;
    }
    __syncthreads();

    // ---- final: (1000x16) @ (16x256) MFMA + relu + masked mean-pool ----
    {
        int wave = t >> 6, lane = t & 63;
        int q = lane >> 4, fl = lane & 15;
        int fglob = wave * 16 + fl;
        float b2f = b2[fglob];
        short8 bfrag = {0, 0, 0, 0, 0, 0, 0, 0};
        if (q < 2) bfrag = *(const short8*)(w2t + fglob * F_MID + q * 8);
        floatx4 zero = {0.f, 0.f, 0.f, 0.f};
        float acc = 0.f;
        for (int tile = 0; tile < 63; tile++) {
            short8 afrag = {0, 0, 0, 0, 0, 0, 0, 0};
            int na = tile * 16 + fl;
            if (q < 2 && na < N_PER)
                afrag = *(const short8*)(fbf + na * F_MID + q * 8);
            floatx4 d = __builtin_amdgcn_mfma_f32_16x16x32_bf16(afrag, bfrag, zero, 0, 0, 0);
#pragma unroll
            for (int r = 0; r < 4; r++) {
                int nd = tile * 16 + q * 4 + r;
                if (nd < N_PER) acc += msk[nd] * fmaxf(d[r] + b2f, 0.f);
            }
        }
        acc += __shfl_xor(acc, 16);
        acc += __shfl_xor(acc, 32);
        if (lane < 16) out[g * F_OUT + fglob] = acc * (1.0f / (float)K_TOP);
    }
}

extern "C" void kernel_launch(void* const* d_in, const int* in_sizes, int n_in,
                              void* d_out, int out_size, void* d_ws, size_t ws_size,
                              hipStream_t stream) {
    const float* x      = (const float*)d_in[0];
    const int*   ei     = (const int*)d_in[1];
    const float* W1     = (const float*)d_in[3];
    const float* b1     = (const float*)d_in[4];
    const float* w_rel  = (const float*)d_in[5];
    const float* b_rel  = (const float*)d_in[6];
    const float* w_root = (const float*)d_in[7];
    const float* W2     = (const float*)d_in[8];
    const float* b2     = (const float*)d_in[9];
    float* out = (float*)d_out;

    char* ws = (char*)d_ws;
    size_t o = 0;
    unsigned short* csr = (unsigned short*)(ws + o); o += (size_t)NG * EPGP * sizeof(unsigned short);
    int*   cntG  = (int*)(ws + o);   o += (size_t)N_NODES * sizeof(int);
    int*   rsG   = (int*)(ws + o);   o += (size_t)N_NODES * sizeof(int);
    float* dis1G = (float*)(ws + o); o += (size_t)N_NODES * sizeof(float);
    float* xw1   = (float*)(ws + o); o += (size_t)N_NODES * F_MID * sizeof(float);

    k_front<<<NG + N_NODES / 16, 256, 0, stream>>>(x, W1, ei, csr, cntG, rsG, dis1G, xw1);
    k_mega<<<NG, 1024, 0, stream>>>(csr, cntG, rsG, dis1G, xw1,
                                    b1, w_rel, b_rel, w_root, W2, b2, out);
}

// Round 5
// 240.679 us; speedup vs baseline: 2.2912x; 1.0132x over previous
//
#include <hip/hip_runtime.h>
#include <math.h>

#define N_NODES 100000
#define NG 100
#define N_PER 1000
#define N_EDGES 3200000
#define EPG 32000
#define EPG4 8000
#define EPGP 35008
#define K_TOP 800
#define F_IN 128
#define F_MID 16
#define F_OUT 256
#define SENT 1000

typedef __attribute__((ext_vector_type(8))) short short8;
typedef __attribute__((ext_vector_type(4))) float floatx4;

__device__ __forceinline__ unsigned short f2bf(float x) {
    union { float f; unsigned int u; } c; c.f = x;
    unsigned int u = c.u;
    u = u + 0x7FFF + ((u >> 16) & 1);
    return (unsigned short)(u >> 16);
}
__device__ __forceinline__ void add4(float4& a, const float4 b) {
    a.x += b.x; a.y += b.y; a.z += b.z; a.w += b.w;
}
// swizzled feat element offset for (node s, channel-quad l): kills 8-way bank conflicts
__device__ __forceinline__ int fidx4(int s, int l) {
    return s * 16 + ((4 * (l + ((s >> 1) & 3))) & 15);
}
// order-preserving float->uint key (ascending)
__device__ __forceinline__ unsigned int fkey(float f) {
    unsigned int u = __float_as_uint(f);
    return (u & 0x80000000u) ? ~u : (u | 0x80000000u);
}

// ============ kernel 1: CSR blocks (1024 thr) + GEMM1 tiles (64 nodes) ============
__global__ __launch_bounds__(1024) void k_front(const float* __restrict__ x,
    const float* __restrict__ W1, const int* __restrict__ ei,
    unsigned short* __restrict__ csr, int* __restrict__ cntG, int* __restrict__ rsG,
    float* __restrict__ dis1G, float* __restrict__ xw1)
{
    int b = blockIdx.x, t = threadIdx.x;
    if (b < NG) {
        __shared__ int cnts[N_PER];
        __shared__ int cur[N_PER];
        __shared__ int rs[N_PER];
        __shared__ int scan[1024];
        int g = b, ebase = g * EPG, nbase = g * N_PER;
        const int4* dst4 = (const int4*)(ei + N_EDGES + ebase);
        const int4* src4 = (const int4*)(ei + ebase);
        int4 dreg[8], sreg[8];
        int ni = 0;
        for (int i = t; i < EPG4; i += 1024) { dreg[ni] = dst4[i]; sreg[ni] = src4[i]; ni++; }
        if (t < N_PER) { cnts[t] = 0; cur[t] = 0; }
        __syncthreads();
        for (int i = 0; i < ni; i++) {
            atomicAdd(&cnts[dreg[i].x - nbase], 1);
            atomicAdd(&cnts[dreg[i].y - nbase], 1);
            atomicAdd(&cnts[dreg[i].z - nbase], 1);
            atomicAdd(&cnts[dreg[i].w - nbase], 1);
        }
        __syncthreads();
        int c = (t < N_PER) ? cnts[t] : 0;
        int c4 = (c + 3) & ~3;
        scan[t] = c4;
        __syncthreads();
        for (int dd = 1; dd < 1024; dd <<= 1) {
            int v = (t >= dd) ? scan[t - dd] : 0;
            __syncthreads();
            scan[t] += v;
            __syncthreads();
        }
        int exc = scan[t] - c4;
        unsigned short* cg = csr + (size_t)g * EPGP;
        if (t < N_PER) {
            rs[t] = exc; rsG[nbase + t] = exc; cntG[nbase + t] = c;
            dis1G[nbase + t] = rsqrtf((float)c + 1.0f);
            for (int q = c; q < c4; q++) cg[exc + q] = (unsigned short)SENT;
        }
        __syncthreads();
        for (int i = 0; i < ni; i++) {
            int dl, p;
            dl = dreg[i].x - nbase; p = rs[dl] + atomicAdd(&cur[dl], 1); cg[p] = (unsigned short)(sreg[i].x - nbase);
            dl = dreg[i].y - nbase; p = rs[dl] + atomicAdd(&cur[dl], 1); cg[p] = (unsigned short)(sreg[i].y - nbase);
            dl = dreg[i].z - nbase; p = rs[dl] + atomicAdd(&cur[dl], 1); cg[p] = (unsigned short)(sreg[i].z - nbase);
            dl = dreg[i].w - nbase; p = rs[dl] + atomicAdd(&cur[dl], 1); cg[p] = (unsigned short)(sreg[i].w - nbase);
        }
    } else {
        __shared__ float xs[64 * 132];
        __shared__ float wsm[F_IN * F_MID];
        long tile = b - NG;
        long n0 = tile * 64;
        int nmax = (int)((N_NODES - n0 < 64) ? (N_NODES - n0) : 64);
        const float* xp = x + n0 * F_IN;
        for (int i = t; i < nmax * F_IN; i += 1024) {
            int n = i >> 7, k = i & 127;
            xs[n * 132 + k] = xp[i];
        }
        for (int i = t; i < F_IN * F_MID; i += 1024) wsm[i] = W1[i];
        __syncthreads();
        int node = t >> 4, j = t & 15;
        if (node < nmax) {
            const float* xr = xs + node * 132;
            float acc = 0.f;
#pragma unroll 16
            for (int k = 0; k < F_IN; k++) acc += xr[k] * wsm[k * F_MID + j];
            xw1[(n0 + node) * F_MID + j] = acc;
        }
    }
}

// ============ kernel 2: all per-graph phases in one block / graph ============
__global__ __launch_bounds__(1024) void k_mega(const unsigned short* __restrict__ csr,
    const int* __restrict__ cntG, const int* __restrict__ rsG,
    const float* __restrict__ dis1G, const float* __restrict__ xw1,
    const float* __restrict__ b1, const float* __restrict__ w_rel,
    const float* __restrict__ b_rel, const float* __restrict__ w_root,
    const float* __restrict__ W2, const float* __restrict__ b2,
    float* __restrict__ out)
{
    __shared__ __align__(16) float feat[(N_PER + 1) * F_MID];     // swizzled rows
    __shared__ __align__(16) unsigned short fbf[N_PER * F_MID];   // logical layout bf16
    __shared__ __align__(16) unsigned short w2t[F_OUT * F_MID];
    __shared__ float sc[N_PER];
    __shared__ float msk[N_PER + 1];
    __shared__ float wsrc[N_PER + 1];
    __shared__ float hw[N_PER + 1];
    __shared__ float hro[N_PER];
    __shared__ float dis2a[N_PER];
    __shared__ float dis1l[N_PER];
    __shared__ int cntl[N_PER];
    __shared__ int rsl[N_PER];
    __shared__ int hist[1024];
    __shared__ float partial[F_OUT];
    __shared__ int sh_b1, sh_r1, sh_b2, sh_r2, sh_len, sh_cntgt;
    __shared__ float sh_thr;

    int t = threadIdx.x, g = blockIdx.x;
    int nbase = g * N_PER;
    const unsigned short* cg = csr + (size_t)g * EPGP;
    int grp = t >> 2, l = t & 3;

    if (t < N_PER) { cntl[t] = cntG[nbase + t]; rsl[t] = rsG[nbase + t]; dis1l[t] = dis1G[nbase + t]; }
    if (t == 0) { sh_cntgt = 0; sh_len = 0; }
    for (int i = t; i < F_OUT * F_MID; i += 1024) {
        int f = i >> 4, jj = i & 15;
        w2t[i] = f2bf(W2[jj * F_OUT + f]);
    }
    __syncthreads();

    // ---- stage feat = xw1 * dis1 (swizzled); zero sentinel row ----
    {
        const float4* xsrc = (const float4*)(xw1 + (size_t)nbase * F_MID);
        for (int i = t; i < N_PER * 4; i += 1024) {
            int n = i >> 2, q = i & 3;
            float4 v = xsrc[i];
            float d = dis1l[n];
            v.x *= d; v.y *= d; v.z *= d; v.w *= d;
            *(float4*)(feat + fidx4(n, q)) = v;
        }
        if (t < 4) { float4 z = {0.f, 0.f, 0.f, 0.f}; *(float4*)(feat + fidx4(SENT, t)) = z; }
    }
    __syncthreads();

    float4 b14 = *(const float4*)(b1 + 4 * l);
    float4 wr4 = *(const float4*)(w_rel + 4 * l);
    float4 wo4 = *(const float4*)(w_root + 4 * l);
    float brel = b_rel[0];

    // ---- conv1 aggregation + relu -> h (in place) ----
    float4 hreg[4];
#pragma unroll
    for (int rr = 0; rr < 4; rr++) {
        int n = grp + 256 * rr;
        if (n < N_PER) {
            int c4 = (cntl[n] + 3) & ~3;
            const unsigned short* cp = cg + rsl[n];
            float4 a0 = {0,0,0,0}, a1 = a0, a2 = a0, a3 = a0;
            for (int k = 0; k < c4; k += 4) {
                uint2 wv = *(const uint2*)(cp + k);
                int s0 = wv.x & 0xFFFF, s1 = wv.x >> 16, s2 = wv.y & 0xFFFF, s3 = wv.y >> 16;
                add4(a0, *(const float4*)(feat + fidx4(s0, l)));
                add4(a1, *(const float4*)(feat + fidx4(s1, l)));
                add4(a2, *(const float4*)(feat + fidx4(s2, l)));
                add4(a3, *(const float4*)(feat + fidx4(s3, l)));
            }
            add4(a0, a1); add4(a2, a3); add4(a0, a2);
            float4 sf = *(const float4*)(feat + fidx4(n, l));
            float di = dis1l[n];
            float4 hv;
            hv.x = fmaxf(fmaf(di, a0.x + sf.x, b14.x), 0.f);
            hv.y = fmaxf(fmaf(di, a0.y + sf.y, b14.y), 0.f);
            hv.z = fmaxf(fmaf(di, a0.z + sf.z, b14.z), 0.f);
            hv.w = fmaxf(fmaf(di, a0.w + sf.w, b14.w), 0.f);
            hreg[rr] = hv;
        }
    }
    __syncthreads();
#pragma unroll
    for (int rr = 0; rr < 4; rr++) {
        int n = grp + 256 * rr;
        if (n < N_PER) *(float4*)(feat + fidx4(n, l)) = hreg[rr];
    }
    __syncthreads();

    // ---- per-node readout scalars: hw = h.w_rel, hro = h.w_root ----
#pragma unroll
    for (int rr = 0; rr < 4; rr++) {
        int n = grp + 256 * rr;
        if (n < N_PER) {
            float4 hv = *(const float4*)(feat + fidx4(n, l));
            float p1 = hv.x * wr4.x + hv.y * wr4.y + hv.z * wr4.z + hv.w * wr4.w;
            float p2 = hv.x * wo4.x + hv.y * wo4.y + hv.z * wo4.z + hv.w * wo4.w;
            p1 += __shfl_xor(p1, 1); p1 += __shfl_xor(p1, 2);
            p2 += __shfl_xor(p2, 1); p2 += __shfl_xor(p2, 2);
            if (l == 0) { hw[n] = p1; hro[n] = p2; }
        }
    }
    if (t == 0) hw[SENT] = 0.f;
    __syncthreads();

    // ---- score: scalar gather of hw over neighbors ----
#pragma unroll
    for (int rr = 0; rr < 4; rr++) {
        int n = grp + 256 * rr;
        if (n < N_PER) {
            int c4 = (cntl[n] + 3) & ~3;
            const unsigned short* cp = cg + rsl[n];
            float sm = 0.f;
            for (int k = 0; k < c4; k += 4) {
                uint2 wv = *(const uint2*)(cp + k);
                int s = (l == 0) ? (int)(wv.x & 0xFFFF) : (l == 1) ? (int)(wv.x >> 16)
                      : (l == 2) ? (int)(wv.y & 0xFFFF) : (int)(wv.y >> 16);
                sm += hw[s];
            }
            sm += __shfl_xor(sm, 1); sm += __shfl_xor(sm, 2);
            if (l == 0) sc[n] = tanhf(sm + hro[n] + brel);
        }
    }
    __syncthreads();

    // ---- top-K threshold via 2-level radix histogram (exact) ----
    unsigned int mykey = (t < N_PER) ? fkey(sc[t]) : 0u;
    hist[t] = 0;
    __syncthreads();
    if (t < N_PER) atomicAdd(&hist[mykey >> 22], 1);
    __syncthreads();
    {   // suffix-sum via reversed Hillis-Steele
        int v0 = hist[t]; __syncthreads();
        hist[1023 - t] = v0; __syncthreads();
        for (int dd = 1; dd < 1024; dd <<= 1) {
            int v = (t >= dd) ? hist[t - dd] : 0;
            __syncthreads(); hist[t] += v; __syncthreads();
        }
        int Sb = hist[1023 - t];
        int Snext = (t == 1023) ? 0 : hist[1022 - t];
        if (Sb >= K_TOP && Snext < K_TOP) { sh_b1 = t; sh_r1 = K_TOP - Snext; }
    }
    __syncthreads();
    int b1v = sh_b1, r1 = sh_r1;
    hist[t] = 0;
    __syncthreads();
    if (t < N_PER && (int)(mykey >> 22) == b1v) atomicAdd(&hist[(mykey >> 12) & 1023], 1);
    __syncthreads();
    {
        int v0 = hist[t]; __syncthreads();
        hist[1023 - t] = v0; __syncthreads();
        for (int dd = 1; dd < 1024; dd <<= 1) {
            int v = (t >= dd) ? hist[t - dd] : 0;
            __syncthreads(); hist[t] += v; __syncthreads();
        }
        int Sb = hist[1023 - t];
        int Snext = (t == 1023) ? 0 : hist[1022 - t];
        if (Sb >= r1 && Snext < r1) { sh_b2 = t; sh_r2 = r1 - Snext; }
    }
    __syncthreads();
    unsigned int pref = ((unsigned int)b1v << 10) | (unsigned int)sh_b2;
    int r2 = sh_r2;
    __syncthreads();
    if (t < N_PER && (mykey >> 12) == pref) { int p = atomicAdd(&sh_len, 1); hist[p] = (int)mykey; }
    __syncthreads();
    {
        int L = sh_len;
        if (t < L) {
            unsigned int k0 = (unsigned int)hist[t];
            int gcnt = 0, ecnt = 0;
            for (int q2 = 0; q2 < L; q2++) {
                unsigned int kq = (unsigned int)hist[q2];
                gcnt += (kq > k0); ecnt += (kq == k0);
            }
            if (gcnt < r2 && r2 <= gcnt + ecnt)
                sh_thr = __uint_as_float((k0 & 0x80000000u) ? (k0 & 0x7FFFFFFFu) : ~k0);
        }
    }
    __syncthreads();
    float thr = sh_thr;

    // ---- mask (ties: lowest index first, top_k semantics) ----
    {
        bool pred = (t < N_PER) && (sc[t] > thr);
        unsigned long long bal = __ballot(pred);
        if ((t & 63) == 0) atomicAdd(&sh_cntgt, (int)__popcll(bal));
    }
    __syncthreads();
    {
        int need = K_TOP - sh_cntgt;
        if (t < N_PER) {
            float v = sc[t];
            float mm;
            if (v > thr) mm = 1.f;
            else if (v < thr) mm = 0.f;
            else {
                int r = 0;
                for (int q2 = 0; q2 < t; q2++) if (sc[q2] == thr) r++;
                mm = (r < need) ? 1.f : 0.f;
            }
            msk[t] = mm;
        }
        if (t == 0) { msk[SENT] = 0.f; wsrc[SENT] = 0.f; }
    }
    __syncthreads();

    // ---- deg2 / dis2 / wsrc (scalar mask gather) ----
#pragma unroll
    for (int rr = 0; rr < 4; rr++) {
        int n = grp + 256 * rr;
        if (n < N_PER) {
            int c4 = (cntl[n] + 3) & ~3;
            const unsigned short* cp = cg + rsl[n];
            float sm = 0.f;
            for (int k = 0; k < c4; k += 4) {
                uint2 wv = *(const uint2*)(cp + k);
                int s = (l == 0) ? (int)(wv.x & 0xFFFF) : (l == 1) ? (int)(wv.x >> 16)
                      : (l == 2) ? (int)(wv.y & 0xFFFF) : (int)(wv.y >> 16);
                sm += msk[s];
            }
            sm += __shfl_xor(sm, 1); sm += __shfl_xor(sm, 2);
            if (l == 0) {
                float d2 = msk[n] * (sm + 1.f);
                float di = (d2 > 0.f) ? rsqrtf(d2) : 0.f;
                dis2a[n] = di;
                wsrc[n] = sc[n] * msk[n] * di;
            }
        }
    }
    __syncthreads();

    // ---- fold wsrc into features: feat2 = h * wsrc ----
    for (int i = t; i < N_PER * 4; i += 1024) {
        int n = i >> 2, q = i & 3;
        float w = wsrc[n];
        float4* p = (float4*)(feat + fidx4(n, q));
        float4 v = *p;
        v.x *= w; v.y *= w; v.z *= w; v.w *= w;
        *p = v;
    }
    __syncthreads();

    // ---- conv2 pre-aggregation: pre = dis2 * (sum feat2[s] + feat2[n]) ----
    float4 preg[4];
#pragma unroll
    for (int rr = 0; rr < 4; rr++) {
        int n = grp + 256 * rr;
        if (n < N_PER) {
            float di = dis2a[n];
            float4 pv = {0,0,0,0};
            if (di != 0.f) {
                int c4 = (cntl[n] + 3) & ~3;
                const unsigned short* cp = cg + rsl[n];
                float4 a0 = {0,0,0,0}, a1 = a0, a2 = a0, a3 = a0;
                for (int k = 0; k < c4; k += 4) {
                    uint2 wv = *(const uint2*)(cp + k);
                    int s0 = wv.x & 0xFFFF, s1 = wv.x >> 16, s2 = wv.y & 0xFFFF, s3 = wv.y >> 16;
                    add4(a0, *(const float4*)(feat + fidx4(s0, l)));
                    add4(a1, *(const float4*)(feat + fidx4(s1, l)));
                    add4(a2, *(const float4*)(feat + fidx4(s2, l)));
                    add4(a3, *(const float4*)(feat + fidx4(s3, l)));
                }
                add4(a0, a1); add4(a2, a3); add4(a0, a2);
                float4 sf = *(const float4*)(feat + fidx4(n, l));
                pv.x = di * (a0.x + sf.x);
                pv.y = di * (a0.y + sf.y);
                pv.z = di * (a0.z + sf.z);
                pv.w = di * (a0.w + sf.w);
            }
            preg[rr] = pv;
        }
    }
    __syncthreads();
#pragma unroll
    for (int rr = 0; rr < 4; rr++) {
        int n = grp + 256 * rr;
        if (n < N_PER) *(float4*)(feat + fidx4(n, l)) = preg[rr];
    }
    __syncthreads();

    // ---- pre -> bf16 logical layout (un-swizzle) ----
    for (int i = t; i < N_PER * 8; i += 1024) {
        int n = i >> 3, cp2 = (i & 7) * 2;
        int phys = n * 16 + ((cp2 + 4 * ((n >> 1) & 3)) & 15);
        float2 v = *(const float2*)(feat + phys);
        unsigned int pk = (unsigned int)f2bf(v.x) | ((unsigned int)f2bf(v.y) << 16);
        ((unsigned int*)fbf)[i] = pk;
    }
    __syncthreads();

    // ---- final: (1000x16)@(16x256) MFMA, 8 col-groups x 2 tile-halves ----
    {
        int wave = t >> 6, lane = t & 63;
        int q = lane >> 4, fl = lane & 15;
        int half = wave >> 3, wcol = wave & 7;
        int c0 = 32 * wcol + fl, c1 = c0 + 16;
        float b2f0 = b2[c0], b2f1 = b2[c1];
        short8 bfrag0 = {0,0,0,0,0,0,0,0}, bfrag1 = bfrag0;
        if (q < 2) {
            bfrag0 = *(const short8*)(w2t + c0 * F_MID + q * 8);
            bfrag1 = *(const short8*)(w2t + c1 * F_MID + q * 8);
        }
        floatx4 zero = {0.f, 0.f, 0.f, 0.f};
        float acc0 = 0.f, acc1 = 0.f;
        int t0 = half ? 32 : 0, t1 = half ? 63 : 32;
        for (int tile = t0; tile < t1; tile++) {
            short8 afrag = {0,0,0,0,0,0,0,0};
            int na = tile * 16 + fl;
            if (q < 2 && na < N_PER)
                afrag = *(const short8*)(fbf + na * F_MID + q * 8);
            floatx4 d0 = __builtin_amdgcn_mfma_f32_16x16x32_bf16(afrag, bfrag0, zero, 0, 0, 0);
            floatx4 d1 = __builtin_amdgcn_mfma_f32_16x16x32_bf16(afrag, bfrag1, zero, 0, 0, 0);
#pragma unroll
            for (int r = 0; r < 4; r++) {
                int nd = tile * 16 + q * 4 + r;
                if (nd < N_PER) {
                    float m = msk[nd];
                    acc0 += m * fmaxf(d0[r] + b2f0, 0.f);
                    acc1 += m * fmaxf(d1[r] + b2f1, 0.f);
                }
            }
        }
        acc0 += __shfl_xor(acc0, 16); acc0 += __shfl_xor(acc0, 32);
        acc1 += __shfl_xor(acc1, 16); acc1 += __shfl_xor(acc1, 32);
        if (half == 0 && lane < 16) { partial[c0] = acc0; partial[c1] = acc1; }
        __syncthreads();
        if (half == 1 && lane < 16) {
            out[g * F_OUT + c0] = (partial[c0] + acc0) * (1.0f / (float)K_TOP);
            out[g * F_OUT + c1] = (partial[c1] + acc1) * (1.0f / (float)K_TOP);
        }
    }
}

extern "C" void kernel_launch(void* const* d_in, const int* in_sizes, int n_in,
                              void* d_out, int out_size, void* d_ws, size_t ws_size,
                              hipStream_t stream) {
    const float* x      = (const float*)d_in[0];
    const int*   ei     = (const int*)d_in[1];
    const float* W1     = (const float*)d_in[3];
    const float* b1     = (const float*)d_in[4];
    const float* w_rel  = (const float*)d_in[5];
    const float* b_rel  = (const float*)d_in[6];
    const float* w_root = (const float*)d_in[7];
    const float* W2     = (const float*)d_in[8];
    const float* b2     = (const float*)d_in[9];
    float* out = (float*)d_out;

    char* ws = (char*)d_ws;
    size_t o = 0;
    unsigned short* csr = (unsigned short*)(ws + o); o += (size_t)NG * EPGP * sizeof(unsigned short);
    int*   cntG  = (int*)(ws + o);   o += (size_t)N_NODES * sizeof(int);
    int*   rsG   = (int*)(ws + o);   o += (size_t)N_NODES * sizeof(int);
    float* dis1G = (float*)(ws + o); o += (size_t)N_NODES * sizeof(float);
    float* xw1   = (float*)(ws + o); o += (size_t)N_NODES * F_MID * sizeof(float);

    int gemm_blocks = (N_NODES + 63) / 64;
    k_front<<<NG + gemm_blocks, 1024, 0, stream>>>(x, W1, ei, csr, cntG, rsG, dis1G, xw1);
    k_mega<<<NG, 1024, 0, stream>>>(csr, cntG, rsG, dis1G, xw1,
                                    b1, w_rel, b_rel, w_root, W2, b2, out);
}